// Round 6
// baseline (3789.550 us; speedup 1.0000x reference)
//
#include <hip/hip_runtime.h>
#include <hip/hip_fp16.h>

#define TT 2048
#define BB 64
#define HH 128

typedef _Float16 f16x8 __attribute__((ext_vector_type(8)));
typedef float f32x4 __attribute__((ext_vector_type(4)));

__device__ __forceinline__ float sigm(float x) {
    return __builtin_amdgcn_rcpf(1.0f + __expf(-x));
}
__device__ __forceinline__ float tanh_f(float x) {
    return 1.0f - 2.0f * __builtin_amdgcn_rcpf(1.0f + __expf(2.0f * x));
}
// LDS-only barrier: no vmcnt drain (HIP __syncthreads drains all global ops).
__device__ __forceinline__ void bar_lds() {
    asm volatile("s_waitcnt lgkmcnt(0)\n\ts_barrier" ::: "memory");
}

__device__ __forceinline__ f16x8 load_frag(const float* rowp, int kt, int lh) {
    const float4* p4 = (const float4*)(rowp + kt * 32 + lh * 8);
    float4 a = p4[0], b = p4[1];
    f16x8 f;
    f[0] = (_Float16)a.x; f[1] = (_Float16)a.y; f[2] = (_Float16)a.z; f[3] = (_Float16)a.w;
    f[4] = (_Float16)b.x; f[5] = (_Float16)b.y; f[6] = (_Float16)b.z; f[7] = (_Float16)b.w;
    return f;
}

// Fully fused 2-layer LSTM, 1 batch per block, 64 blocks. L1 lags L0 by one
// step: at interval i, L0 runs step i and L1 runs step i-1. The A-fragment av
// (= h0[i-1], lanes c==0 read 4 masked ds_read_b128) feeds BOTH L0's hh-matvec
// (Bf) and L1's ih-projection (Bi) -> k_proj and all h1/g1 HBM traffic gone.
// MFMA 16x16x32_f16, M=1: N-tile t2 = gate, col c = unit-in-tile; lane's 4
// accs = 4 gates of unit un = 16w+c. One LDS barrier per interval.
__global__ __launch_bounds__(512, 2) void k_fused(
    const float* __restrict__ x, const int* __restrict__ lengths,
    const float* __restrict__ ff_w, const float* __restrict__ ff_b,
    const float* __restrict__ W_ih0, const float* __restrict__ W_hh0,
    const float* __restrict__ b0, const float* __restrict__ W_ih1,
    const float* __restrict__ W_hh1, const float* __restrict__ b1,
    float* __restrict__ pooled) {
    const int b = blockIdx.x;
    const int tid = threadIdx.x;
    const int w = tid >> 6;
    const int lane = tid & 63;
    const int c = lane & 15;
    const int lh = lane >> 4;
    const int un = 16 * w + c;
    __shared__ float xs[TT];
    __shared__ _Float16 Hb0[2][HH];
    __shared__ _Float16 Hb1[2][HH];

    for (int i = tid; i < TT; i += 512) xs[i] = x[b * TT + i];
    if (tid < 2 * HH) {
        ((_Float16*)Hb0)[tid] = (_Float16)0.f;
        ((_Float16*)Hb1)[tid] = (_Float16)0.f;
    }

    f16x8 Bf[4][4], Bi[4][4], Bh[4][4];
    float v[4], u0[4], bia[4];
#pragma unroll
    for (int t2 = 0; t2 < 4; ++t2) {
        const int r = t2 * HH + un;
#pragma unroll
        for (int kt = 0; kt < 4; ++kt) {
            Bf[t2][kt] = load_frag(W_hh0 + r * HH, kt, lh);
            Bi[t2][kt] = load_frag(W_ih1 + r * HH, kt, lh);
            Bh[t2][kt] = load_frag(W_hh1 + r * HH, kt, lh);
        }
        const float* wi = W_ih0 + r * HH;
        float vv = 0.f, uu = 0.f;
        for (int k = 0; k < HH; ++k) { vv += wi[k] * ff_w[k]; uu += wi[k] * ff_b[k]; }
        v[t2] = vv;
        u0[t2] = uu + b0[r];
        bia[t2] = b1[r];
    }
    float cst0 = 0.f, cst1 = 0.f, mean = 0.f, mx = -1e30f, last = 0.f;
    const int len = lengths[b];
    const bool ard = (c == 0);     // A-fragment reader lanes {0,16,32,48}
    const bool wr16 = (lane < 16); // real-row (m=0) lanes
    f16x8 av[4];
#pragma unroll
    for (int kt = 0; kt < 4; ++kt) av[kt] = (f16x8){0, 0, 0, 0, 0, 0, 0, 0};
    __syncthreads();

    // interval 0 (peel): L0 step 0 from zero state -> pre = x0*v + u0 directly
    {
        const float xt = xs[0];
        float gi = sigm(xt * v[0] + u0[0]), gf = sigm(xt * v[1] + u0[1]);
        float gg = tanh_f(xt * v[2] + u0[2]), go = sigm(xt * v[3] + u0[3]);
        cst0 = gi * gg;  // f*0 + i*g
        float h0n = go * tanh_f(cst0);
        if (wr16) Hb0[1][un] = (_Float16)h0n;
        bar_lds();
    }

    // intervals i = 1..len: L0 step i (garbage past len-1, harmless),
    // L1 step i-1 (always real). RB_ == i&1.
#define STEP(I_, RB_)                                                           \
    do {                                                                        \
        if (ard) {                                                              \
            _Pragma("unroll") for (int kt = 0; kt < 4; ++kt)                    \
                av[kt] = *(const f16x8*)&Hb0[RB_][kt * 32 + lh * 8];            \
        }                                                                       \
        const int xi = ((I_) < len) ? (I_) : (len - 1);                         \
        const float xt = xs[xi];                                                \
        f32x4 acc[4];                                                           \
        _Pragma("unroll") for (int t2 = 0; t2 < 4; ++t2) {                      \
            float ci = xt * v[t2] + u0[t2];                                     \
            acc[t2][0] = ci; acc[t2][1] = ci; acc[t2][2] = ci; acc[t2][3] = ci; \
        }                                                                       \
        _Pragma("unroll") for (int t2 = 0; t2 < 4; ++t2) {                      \
            _Pragma("unroll") for (int kt = 0; kt < 4; ++kt)                    \
                acc[t2] = __builtin_amdgcn_mfma_f32_16x16x32_f16(               \
                    av[kt], Bf[t2][kt], acc[t2], 0, 0, 0);                      \
        }                                                                       \
        float p0 = acc[0][0], p1 = acc[1][0], p2 = acc[2][0], p3 = acc[3][0];   \
        _Pragma("unroll") for (int t2 = 0; t2 < 4; ++t2) {                      \
            float ci = bia[t2];                                                 \
            acc[t2][0] = ci; acc[t2][1] = ci; acc[t2][2] = ci; acc[t2][3] = ci; \
        }                                                                       \
        _Pragma("unroll") for (int t2 = 0; t2 < 4; ++t2) {                      \
            _Pragma("unroll") for (int kt = 0; kt < 4; ++kt)                    \
                acc[t2] = __builtin_amdgcn_mfma_f32_16x16x32_f16(               \
                    av[kt], Bi[t2][kt], acc[t2], 0, 0, 0);                      \
        }                                                                       \
        {                                                                       \
            float gi = sigm(p0), gf = sigm(p1), gg = tanh_f(p2), go = sigm(p3); \
            cst0 = gf * cst0 + gi * gg;                                         \
            float h0n = go * tanh_f(cst0);                                      \
            if (wr16) Hb0[(RB_) ^ 1][un] = (_Float16)h0n;                       \
        }                                                                       \
        if (ard) {                                                              \
            _Pragma("unroll") for (int kt = 0; kt < 4; ++kt)                    \
                av[kt] = *(const f16x8*)&Hb1[RB_][kt * 32 + lh * 8];            \
        }                                                                       \
        _Pragma("unroll") for (int t2 = 0; t2 < 4; ++t2) {                      \
            _Pragma("unroll") for (int kt = 0; kt < 4; ++kt)                    \
                acc[t2] = __builtin_amdgcn_mfma_f32_16x16x32_f16(               \
                    av[kt], Bh[t2][kt], acc[t2], 0, 0, 0);                      \
        }                                                                       \
        {                                                                       \
            float gi = sigm(acc[0][0]), gf = sigm(acc[1][0]);                   \
            float gg = tanh_f(acc[2][0]), go = sigm(acc[3][0]);                 \
            cst1 = gf * cst1 + gi * gg;                                         \
            float h1n = go * tanh_f(cst1);                                      \
            if (wr16) Hb1[(RB_) ^ 1][un] = (_Float16)h1n;                       \
            mean += h1n;                                                        \
            mx = fmaxf(mx, h1n);                                                \
            if ((I_) == len) last = h1n;                                        \
        }                                                                       \
        bar_lds();                                                              \
    } while (0)

    int i = 1;
    for (; i + 1 <= len; i += 2) {
        STEP(i, 1);
        STEP(i + 1, 0);
    }
    if (i <= len) STEP(i, 1);
#undef STEP

    if (wr16) {
        pooled[b * 384 + un] = mean / (float)len;
        pooled[b * 384 + 128 + un] = mx;
        pooled[b * 384 + 256 + un] = last;
    }
}

// ---------------- head: [B,3H] @ [3H,C]^T + bias ----------------
__global__ __launch_bounds__(448) void k_head(
    const float* __restrict__ pooled, const float* __restrict__ lin_w,
    const float* __restrict__ lin_b, float* __restrict__ out) {
    int tid = threadIdx.x;  // 448 = 64*7
    int b = tid / 7, cc = tid % 7;
    const float* p = pooled + b * 384;
    const float* wr = lin_w + cc * 384;
    float a0 = 0.f, a1 = 0.f, a2 = 0.f, a3 = 0.f;
#pragma unroll
    for (int k = 0; k < 384; k += 4) {
        a0 += p[k + 0] * wr[k + 0];
        a1 += p[k + 1] * wr[k + 1];
        a2 += p[k + 2] * wr[k + 2];
        a3 += p[k + 3] * wr[k + 3];
    }
    out[tid] = lin_b[cc] + ((a0 + a1) + (a2 + a3));
}

extern "C" void kernel_launch(void* const* d_in, const int* in_sizes, int n_in,
                              void* d_out, int out_size, void* d_ws, size_t ws_size,
                              hipStream_t stream) {
    const float* x     = (const float*)d_in[0];
    const int*   lens  = (const int*)d_in[1];
    const float* ff_w  = (const float*)d_in[2];
    const float* ff_b  = (const float*)d_in[3];
    const float* W_ih0 = (const float*)d_in[4];
    const float* W_hh0 = (const float*)d_in[5];
    const float* b0    = (const float*)d_in[6];
    const float* W_ih1 = (const float*)d_in[7];
    const float* W_hh1 = (const float*)d_in[8];
    const float* b1    = (const float*)d_in[9];
    const float* lin_w = (const float*)d_in[10];
    const float* lin_b = (const float*)d_in[11];
    float* out = (float*)d_out;

    float* pooled = (float*)d_ws;  // [64*384] floats

    k_fused<<<dim3(BB), dim3(512), 0, stream>>>(
        x, lens, ff_w, ff_b, W_ih0, W_hh0, b0, W_ih1, W_hh1, b1, pooled);
    k_head<<<dim3(1), dim3(448), 0, stream>>>(pooled, lin_w, lin_b, out);
}